// Round 1
// baseline (1520.333 us; speedup 1.0000x reference)
//
#include <hip/hip_runtime.h>
#include <hip/hip_bf16.h>

#define B_ 4
#define S_ 4096
#define DIN 1024
#define NS 4
#define KS 256
#define CHUNK 256
#define NCHUNK (S_/CHUNK)   // 16
#define INV16 0.0625f

// ---------- bf16 helpers (raw ushort storage) ----------
__device__ __forceinline__ float b2f(unsigned short u) {
  union { unsigned int u; float f; } cv;
  cv.u = ((unsigned int)u) << 16;
  return cv.f;
}
__device__ __forceinline__ unsigned short f2b(float f) {
  union { float f; unsigned int u; } cv; cv.f = f;
  unsigned int u = cv.u;
  u += 0x7fffu + ((u >> 16) & 1u);   // round-to-nearest-even
  return (unsigned short)(u >> 16);
}

__device__ __forceinline__ void a_base_of(int n, float& ar, float& ai) {
  // r = [1.0, linspace(0.999,0.9,3)], th = [0.0, linspace(0.01,1.0,3)]
  const float r[4]  = {1.0f, 0.999f, 0.9495f, 0.9f};
  const float th[4] = {0.0f, 0.01f, 0.505f, 1.0f};
  ar = r[n] * cosf(th[n]);
  ai = r[n] * sinf(th[n]);
}

// ---------- GEMM1: C[r, n*256+k] = x[r,:] @ W[n][:,k] + bias; 3 matrices via blockIdx.z ----------
__global__ __launch_bounds__(256) void gemm1_kernel(
    const float* __restrict__ x,
    const float* __restrict__ Wg1, const float* __restrict__ bg1,
    const float* __restrict__ Wre, const float* __restrict__ bre,
    const float* __restrict__ Wim, const float* __restrict__ bim,
    unsigned short* __restrict__ g1, unsigned short* __restrict__ dre,
    unsigned short* __restrict__ dimv)
{
  const int mat = blockIdx.z;
  const float* W    = (mat==0) ? Wg1 : (mat==1 ? Wre : Wim);
  const float* bias = (mat==0) ? bg1 : (mat==1 ? bre : bim);
  unsigned short* dst = (mat==0) ? g1 : (mat==1 ? dre : dimv);

  const int ct = blockIdx.x;          // 0..15  (n*4 + ktile)
  const int rt = blockIdx.y;          // 0..255
  const int n = ct >> 2;
  const int col0 = (ct & 3) * 64;
  const int row0 = rt * 64;
  const float* Wn = W + (size_t)n * DIN * KS;

  __shared__ alignas(16) float As[16][64];
  __shared__ alignas(16) float Bs[16][64];

  const int tid = threadIdx.x;
  const int tx = tid & 15;
  const int ty = tid >> 4;

  float acc[4][4] = {};

  for (int k0 = 0; k0 < DIN; k0 += 16) {
    {
      const int lr = tid >> 2;
      const int lc = (tid & 3) << 2;
      const float4 v = *reinterpret_cast<const float4*>(x + (size_t)(row0+lr)*DIN + k0 + lc);
      As[lc+0][lr] = v.x; As[lc+1][lr] = v.y; As[lc+2][lr] = v.z; As[lc+3][lr] = v.w;
    }
    {
      const int kk = tid >> 4;
      const int c4 = (tid & 15) << 2;
      *reinterpret_cast<float4*>(&Bs[kk][c4]) =
          *reinterpret_cast<const float4*>(Wn + (size_t)(k0+kk)*KS + col0 + c4);
    }
    __syncthreads();
#pragma unroll
    for (int kk = 0; kk < 16; ++kk) {
      const float4 av = *reinterpret_cast<const float4*>(&As[kk][ty<<2]);
      const float4 bv = *reinterpret_cast<const float4*>(&Bs[kk][tx<<2]);
      const float a[4] = {av.x, av.y, av.z, av.w};
      const float b[4] = {bv.x, bv.y, bv.z, bv.w};
#pragma unroll
      for (int i = 0; i < 4; ++i)
#pragma unroll
        for (int j = 0; j < 4; ++j)
          acc[i][j] = fmaf(a[i], b[j], acc[i][j]);
    }
    __syncthreads();
  }

#pragma unroll
  for (int i = 0; i < 4; ++i) {
    const int row = row0 + (ty<<2) + i;
    const int bb = row >> 12;          // row / 4096
    const int s  = row & 4095;
    ushort4 pk;
    float v0, v1, v2, v3;
    {
      const int cb = col0 + (tx<<2);
      v0 = acc[i][0] + bias[n*KS + cb+0];
      v1 = acc[i][1] + bias[n*KS + cb+1];
      v2 = acc[i][2] + bias[n*KS + cb+2];
      v3 = acc[i][3] + bias[n*KS + cb+3];
      if (mat == 0) { v0=fmaxf(v0,0.f); v1=fmaxf(v1,0.f); v2=fmaxf(v2,0.f); v3=fmaxf(v3,0.f); }
      pk.x = f2b(v0); pk.y = f2b(v1); pk.z = f2b(v2); pk.w = f2b(v3);
      const size_t idx = (((size_t)(bb*NS + n))*S_ + s)*KS + cb;
      *reinterpret_cast<ushort4*>(dst + idx) = pk;
    }
  }
}

// ---------- GEMM2: omg = sigmoid(-(g1 @ Wg2[n] + bg2[n])) = 1 - gate ----------
__global__ __launch_bounds__(256) void gemm2_kernel(
    const unsigned short* __restrict__ g1,
    const float* __restrict__ Wg2, const float* __restrict__ bg2,
    unsigned short* __restrict__ omg)
{
  const int ct = blockIdx.x;          // 0..15
  const int rt = blockIdx.y;          // 0..255
  const int n = ct >> 2;
  const int col0 = (ct & 3) * 64;
  const int row0 = rt * 64;
  const int bb = row0 >> 12;
  const int s0 = row0 & 4095;
  const unsigned short* Arow = g1 + (((size_t)(bb*NS + n))*S_ + s0)*KS;
  const float* Wn = Wg2 + (size_t)n * KS * KS;

  __shared__ alignas(16) float As[16][64];
  __shared__ alignas(16) float Bs[16][64];

  const int tid = threadIdx.x;
  const int tx = tid & 15;
  const int ty = tid >> 4;

  float acc[4][4] = {};

  for (int k0 = 0; k0 < KS; k0 += 16) {
    {
      const int lr = tid >> 2;
      const int lc = (tid & 3) << 2;
      const ushort4 v = *reinterpret_cast<const ushort4*>(Arow + (size_t)lr*KS + k0 + lc);
      As[lc+0][lr] = b2f(v.x); As[lc+1][lr] = b2f(v.y);
      As[lc+2][lr] = b2f(v.z); As[lc+3][lr] = b2f(v.w);
    }
    {
      const int kk = tid >> 4;
      const int c4 = (tid & 15) << 2;
      *reinterpret_cast<float4*>(&Bs[kk][c4]) =
          *reinterpret_cast<const float4*>(Wn + (size_t)(k0+kk)*KS + col0 + c4);
    }
    __syncthreads();
#pragma unroll
    for (int kk = 0; kk < 16; ++kk) {
      const float4 av = *reinterpret_cast<const float4*>(&As[kk][ty<<2]);
      const float4 bv = *reinterpret_cast<const float4*>(&Bs[kk][tx<<2]);
      const float a[4] = {av.x, av.y, av.z, av.w};
      const float b[4] = {bv.x, bv.y, bv.z, bv.w};
#pragma unroll
      for (int i = 0; i < 4; ++i)
#pragma unroll
        for (int j = 0; j < 4; ++j)
          acc[i][j] = fmaf(a[i], b[j], acc[i][j]);
    }
    __syncthreads();
  }

#pragma unroll
  for (int i = 0; i < 4; ++i) {
    const int s = s0 + (ty<<2) + i;
    const int cb = col0 + (tx<<2);
    ushort4 pk;
#pragma unroll
    for (int j = 0; j < 4; ++j) {
      const float v = acc[i][j] + bg2[n*KS + cb + j];
      const float g = 1.0f / (1.0f + expf(v));   // 1 - sigmoid(v)
      ((unsigned short*)&pk)[j] = f2b(g);
    }
    const size_t idx = (((size_t)(bb*NS + n))*S_ + s)*KS + cb;
    *reinterpret_cast<ushort4*>(omg + idx) = pk;
  }
}

// ---------- Scan phase 1: per-chunk affine aggregates (A, B) ----------
__global__ __launch_bounds__(256) void scan_phase1(
    const unsigned short* __restrict__ omg,
    const unsigned short* __restrict__ dre,
    const unsigned short* __restrict__ dimv,
    float4* __restrict__ carry)
{
  const int c = blockIdx.x, n = blockIdx.y, bb = blockIdx.z;
  const int k = threadIdx.x;
  float ar, ai; a_base_of(n, ar, ai);
  size_t base = (((size_t)(bb*NS + n))*S_ + (size_t)c*CHUNK)*KS + k;
  float Are = 1.f, Aim = 0.f, Bre = 0.f, Bim = 0.f;
  for (int s = 0; s < CHUNK; ++s) {
    const size_t p = base + (size_t)s*KS;
    const float g  = b2f(omg[p]);
    const float are = g*ar, aie = g*ai;
    const float br = g * b2f(dre[p])  * INV16;
    const float bi = g * b2f(dimv[p]) * INV16;
    const float nAre = Are*are - Aim*aie;
    const float nAim = Are*aie + Aim*are;
    const float nBre = fmaf(are, Bre, fmaf(-aie, Bim, br));
    const float nBim = fmaf(are, Bim, fmaf( aie, Bre, bi));
    Are = nAre; Aim = nAim; Bre = nBre; Bim = nBim;
  }
  carry[(((size_t)(bb*NS + n))*NCHUNK + c)*KS + k] = make_float4(Are, Aim, Bre, Bim);
}

// ---------- Scan phase 2: sequential carry over chunks per chain ----------
__global__ __launch_bounds__(256) void scan_carry(
    const float4* __restrict__ carry, float2* __restrict__ Hst)
{
  const int idx = blockIdx.x*256 + threadIdx.x;   // 0..4095
  const int k  = idx & 255;
  const int bn = idx >> 8;                        // b*4+n, 0..15
  float hre = 0.f, him = 0.f;
  const size_t base = ((size_t)bn)*NCHUNK*KS + k;
  for (int c = 0; c < NCHUNK; ++c) {
    Hst[base + (size_t)c*KS] = make_float2(hre, him);
    const float4 ab = carry[base + (size_t)c*KS];
    const float nre = fmaf(ab.x, hre, fmaf(-ab.y, him, ab.z));
    const float nim = fmaf(ab.x, him, fmaf( ab.y, hre, ab.w));
    hre = nre; him = nim;
  }
}

// ---------- Scan phase 3: replay with chunk-entry state, write output ----------
__global__ __launch_bounds__(256) void scan_phase3(
    const unsigned short* __restrict__ omg,
    const unsigned short* __restrict__ dre,
    const unsigned short* __restrict__ dimv,
    const float2* __restrict__ Hst,
    float* __restrict__ out)
{
  const int c = blockIdx.x, n = blockIdx.y, bb = blockIdx.z;
  const int k = threadIdx.x;
  float ar, ai; a_base_of(n, ar, ai);
  const float2 h0 = Hst[(((size_t)(bb*NS + n))*NCHUNK + c)*KS + k];
  float hre = h0.x, him = h0.y;
  size_t base = (((size_t)(bb*NS + n))*S_ + (size_t)c*CHUNK)*KS + k;
  size_t ob = (((size_t)bb)*S_ + (size_t)c*CHUNK)*2048 + (size_t)n*512 + k;
  for (int s = 0; s < CHUNK; ++s) {
    const size_t p = base + (size_t)s*KS;
    const float g  = b2f(omg[p]);
    const float are = g*ar, aie = g*ai;
    const float br = g * b2f(dre[p])  * INV16;
    const float bi = g * b2f(dimv[p]) * INV16;
    const float nre = fmaf(are, hre, fmaf(-aie, him, br));
    const float nim = fmaf(are, him, fmaf( aie, hre, bi));
    hre = nre; him = nim;
    out[ob + (size_t)s*2048      ] = hre;
    out[ob + (size_t)s*2048 + 256] = him;
  }
}

extern "C" void kernel_launch(void* const* d_in, const int* in_sizes, int n_in,
                              void* d_out, int out_size, void* d_ws, size_t ws_size,
                              hipStream_t stream) {
  const float* x   = (const float*)d_in[0];
  const float* Wg1 = (const float*)d_in[1];
  const float* bg1 = (const float*)d_in[2];
  const float* Wg2 = (const float*)d_in[3];
  const float* bg2 = (const float*)d_in[4];
  const float* Wre = (const float*)d_in[5];
  const float* bre = (const float*)d_in[6];
  const float* Wim = (const float*)d_in[7];
  const float* bim = (const float*)d_in[8];
  float* out = (float*)d_out;

  char* ws = (char*)d_ws;
  const size_t BUF = (size_t)B_*NS*S_*KS*sizeof(unsigned short);  // 33,554,432 B
  unsigned short* g1   = (unsigned short*)(ws);
  unsigned short* dre  = (unsigned short*)(ws + BUF);
  unsigned short* dimv = (unsigned short*)(ws + 2*BUF);
  unsigned short* omg  = (unsigned short*)(ws + 3*BUF);
  float4* carry = (float4*)(ws + 4*BUF);
  float2* Hst   = (float2*)(ws + 4*BUF + (size_t)B_*NS*NCHUNK*KS*sizeof(float4));

  gemm1_kernel<<<dim3(16, 256, 3), 256, 0, stream>>>(x, Wg1, bg1, Wre, bre, Wim, bim,
                                                     g1, dre, dimv);
  gemm2_kernel<<<dim3(16, 256, 1), 256, 0, stream>>>(g1, Wg2, bg2, omg);
  scan_phase1<<<dim3(NCHUNK, NS, B_), 256, 0, stream>>>(omg, dre, dimv, carry);
  scan_carry<<<16, 256, 0, stream>>>(carry, Hst);
  scan_phase3<<<dim3(NCHUNK, NS, B_), 256, 0, stream>>>(omg, dre, dimv, Hst, out);
}

// Round 2
// 247.171 us; speedup vs baseline: 6.1509x; 6.1509x over previous
//
#include <hip/hip_runtime.h>
#include <hip/hip_bf16.h>

#define B_ 4
#define S_ 4096
#define DIN 1024
#define NS 4
#define KS 256
#define CHUNK 128
#define NCHUNK (S_/CHUNK)   // 32
#define INV16 0.0625f

typedef __bf16 bf16x8 __attribute__((ext_vector_type(8)));
typedef float f32x4 __attribute__((ext_vector_type(4)));

// ---------- bf16 helpers (raw ushort storage) ----------
__device__ __forceinline__ float b2f(unsigned short u) {
  union { unsigned int u; float f; } cv;
  cv.u = ((unsigned int)u) << 16;
  return cv.f;
}
__device__ __forceinline__ unsigned short f2b(float f) {
  union { float f; unsigned int u; } cv; cv.f = f;
  unsigned int u = cv.u;
  u += 0x7fffu + ((u >> 16) & 1u);   // round-to-nearest-even
  return (unsigned short)(u >> 16);
}

__device__ __forceinline__ void a_base_of(int n, float& ar, float& ai) {
  const float r[4]  = {1.0f, 0.999f, 0.9495f, 0.9f};
  const float th[4] = {0.0f, 0.01f, 0.505f, 1.0f};
  ar = r[n] * cosf(th[n]);
  ai = r[n] * sinf(th[n]);
}

__device__ __forceinline__ void glds16(const unsigned short* g, unsigned short* l) {
  __builtin_amdgcn_global_load_lds(
      (const __attribute__((address_space(1))) unsigned int*)g,
      (__attribute__((address_space(3))) unsigned int*)l, 16, 0, 0);
}

// ---------- conversion kernels ----------
__global__ __launch_bounds__(256) void cvt_x(const float* __restrict__ x,
                                             unsigned short* __restrict__ xb) {
  const size_t i = ((size_t)blockIdx.x*256 + threadIdx.x)*4;
  const float4 v = *reinterpret_cast<const float4*>(x + i);
  ushort4 o; o.x=f2b(v.x); o.y=f2b(v.y); o.z=f2b(v.z); o.w=f2b(v.w);
  *reinterpret_cast<ushort4*>(xb + i) = o;
}

// W[mat][n][1024 d][256 k] fp32  ->  Wb[mat*1024+n*256+k][1024 d] bf16
__global__ __launch_bounds__(256) void cvt_w1(const float* __restrict__ Wg1,
                                              const float* __restrict__ Wre,
                                              const float* __restrict__ Wim,
                                              unsigned short* __restrict__ Wb) {
  const int mn = blockIdx.z, mat = mn >> 2, n = mn & 3;
  const float* W = (mat==0) ? Wg1 : (mat==1 ? Wre : Wim);
  const float* src = W + (size_t)n*(DIN*KS);                     // [1024][256]
  unsigned short* dst = Wb + (size_t)(mat*1024 + n*KS)*DIN;      // [256][1024]
  __shared__ float t[32][33];
  const int tx = threadIdx.x & 31, ty = threadIdx.x >> 5;        // ty in [0,8)
  const int d0 = blockIdx.y*32, k0 = blockIdx.x*32;
#pragma unroll
  for (int p = 0; p < 4; ++p)
    t[ty + p*8][tx] = src[(size_t)(d0 + ty + p*8)*KS + k0 + tx];
  __syncthreads();
#pragma unroll
  for (int p = 0; p < 4; ++p)
    dst[(size_t)(k0 + ty + p*8)*DIN + d0 + tx] = f2b(t[tx][ty + p*8]);
}

// Wg2[n][256 kin][256 kout] fp32 -> Wg2t[n][256 kout][256 kin] bf16
__global__ __launch_bounds__(256) void cvt_wg2(const float* __restrict__ Wg2,
                                               unsigned short* __restrict__ Wg2t) {
  const int n = blockIdx.z;
  const float* src = Wg2 + (size_t)n*(KS*KS);
  unsigned short* dst = Wg2t + (size_t)n*(KS*KS);
  __shared__ float t[32][33];
  const int tx = threadIdx.x & 31, ty = threadIdx.x >> 5;
  const int ki0 = blockIdx.y*32, ko0 = blockIdx.x*32;
#pragma unroll
  for (int p = 0; p < 4; ++p)
    t[ty + p*8][tx] = src[(size_t)(ki0 + ty + p*8)*KS + ko0 + tx];
  __syncthreads();
#pragma unroll
  for (int p = 0; p < 4; ++p)
    dst[(size_t)(ko0 + ty + p*8)*KS + ki0 + tx] = f2b(t[tx][ty + p*8]);
}

// ---------- GEMM1 (MFMA): C[16384][3072] = xb @ Wb^T, scatter to g1/dre/dim ----------
__global__ __launch_bounds__(256) void gemm1_mfma(
    const unsigned short* __restrict__ xb,   // [16384][1024]
    const unsigned short* __restrict__ Wb,   // [3072][1024]
    const float* __restrict__ bg1, const float* __restrict__ bre,
    const float* __restrict__ bim,
    unsigned short* __restrict__ g1, unsigned short* __restrict__ dre,
    unsigned short* __restrict__ dimv)
{
  __shared__ unsigned short Asm[128*32];
  __shared__ unsigned short Bsm[128*32];
  const int col0 = blockIdx.x * 128;   // 0..3071
  const int row0 = blockIdx.y * 128;   // 0..16383
  const int tid  = threadIdx.x;
  const int lane = tid & 63, wid = tid >> 6;
  const int wr = wid >> 1, wc = wid & 1;
  const int fr = lane & 15, fq = lane >> 4;

  const int roff = tid >> 2;           // 0..63
  const int koff = (tid & 3) << 3;     // 0,8,16,24

  const unsigned short* gA = xb + (size_t)(row0 + roff)*DIN + koff;
  const unsigned short* gB = Wb + (size_t)(col0 + roff)*DIN + koff;
  unsigned short* lA0 = &Asm[(size_t)wid*512];
  unsigned short* lA1 = &Asm[2048 + (size_t)wid*512];
  unsigned short* lB0 = &Bsm[(size_t)wid*512];
  unsigned short* lB1 = &Bsm[2048 + (size_t)wid*512];

  f32x4 acc[4][4];
#pragma unroll
  for (int m = 0; m < 4; ++m)
#pragma unroll
    for (int n = 0; n < 4; ++n) acc[m][n] = (f32x4){0.f,0.f,0.f,0.f};

  for (int k0 = 0; k0 < DIN; k0 += 32) {
    glds16(gA + k0,            lA0);
    glds16(gA + k0 + 64*DIN,   lA1);
    glds16(gB + k0,            lB0);
    glds16(gB + k0 + 64*DIN,   lB1);
    __syncthreads();
    bf16x8 af[4], bfv[4];
#pragma unroll
    for (int m = 0; m < 4; ++m)
      af[m] = *(const bf16x8*)&Asm[(wr*64 + m*16 + fr)*32 + fq*8];
#pragma unroll
    for (int n = 0; n < 4; ++n)
      bfv[n] = *(const bf16x8*)&Bsm[(wc*64 + n*16 + fr)*32 + fq*8];
#pragma unroll
    for (int m = 0; m < 4; ++m)
#pragma unroll
      for (int n = 0; n < 4; ++n)
        acc[m][n] = __builtin_amdgcn_mfma_f32_16x16x32_bf16(af[m], bfv[n], acc[m][n], 0, 0, 0);
    __syncthreads();
  }

  // block-uniform output routing
  const int mat = col0 >> 10;
  const int nsc = (col0 & 1023) >> 8;
  const float* bias = (mat==0) ? bg1 : (mat==1 ? bre : bim);
  unsigned short* dst = (mat==0) ? g1 : (mat==1 ? dre : dimv);

#pragma unroll
  for (int m = 0; m < 4; ++m) {
    const int grow_base = row0 + wr*64 + m*16 + fq*4;
#pragma unroll
    for (int n = 0; n < 4; ++n) {
      const int kk = (col0 & 255) + wc*64 + n*16 + fr;
      const float bv = bias[nsc*KS + kk];
#pragma unroll
      for (int reg = 0; reg < 4; ++reg) {
        const int grow = grow_base + reg;
        const int bb = grow >> 12, s = grow & 4095;
        float v = acc[m][n][reg] + bv;
        if (mat == 0) v = fmaxf(v, 0.f);
        dst[(((size_t)(bb*NS + nsc))*S_ + s)*KS + kk] = f2b(v);
      }
    }
  }
}

// ---------- GEMM2 (MFMA): omg = 1 - sigmoid(g1 @ Wg2 + bg2) ----------
__global__ __launch_bounds__(256) void gemm2_mfma(
    const unsigned short* __restrict__ g1,     // ((bb*NS+n)*S+s)*256 + k
    const unsigned short* __restrict__ Wg2t,   // [n][256 kout][256 kin]
    const float* __restrict__ bg2,
    unsigned short* __restrict__ omg)
{
  __shared__ unsigned short Asm[128*32];
  __shared__ unsigned short Bsm[128*32];
  const int nz   = blockIdx.z;
  const int col0 = blockIdx.x * 128;   // 0 or 128
  const int row0 = blockIdx.y * 128;   // 0..16383 (bb,s)
  const int bb = row0 >> 12, s0 = row0 & 4095;
  const int tid  = threadIdx.x;
  const int lane = tid & 63, wid = tid >> 6;
  const int wr = wid >> 1, wc = wid & 1;
  const int fr = lane & 15, fq = lane >> 4;

  const int roff = tid >> 2;
  const int koff = (tid & 3) << 3;

  const unsigned short* Abase = g1 + (((size_t)(bb*NS + nz))*S_ + s0)*KS;
  const unsigned short* Bbase = Wg2t + (size_t)nz*KS*KS;
  const unsigned short* gA = Abase + (size_t)roff*KS + koff;
  const unsigned short* gB = Bbase + (size_t)(col0 + roff)*KS + koff;
  unsigned short* lA0 = &Asm[(size_t)wid*512];
  unsigned short* lA1 = &Asm[2048 + (size_t)wid*512];
  unsigned short* lB0 = &Bsm[(size_t)wid*512];
  unsigned short* lB1 = &Bsm[2048 + (size_t)wid*512];

  f32x4 acc[4][4];
#pragma unroll
  for (int m = 0; m < 4; ++m)
#pragma unroll
    for (int n = 0; n < 4; ++n) acc[m][n] = (f32x4){0.f,0.f,0.f,0.f};

  for (int k0 = 0; k0 < KS; k0 += 32) {
    glds16(gA + k0,           lA0);
    glds16(gA + k0 + 64*KS,   lA1);
    glds16(gB + k0,           lB0);
    glds16(gB + k0 + 64*KS,   lB1);
    __syncthreads();
    bf16x8 af[4], bfv[4];
#pragma unroll
    for (int m = 0; m < 4; ++m)
      af[m] = *(const bf16x8*)&Asm[(wr*64 + m*16 + fr)*32 + fq*8];
#pragma unroll
    for (int n = 0; n < 4; ++n)
      bfv[n] = *(const bf16x8*)&Bsm[(wc*64 + n*16 + fr)*32 + fq*8];
#pragma unroll
    for (int m = 0; m < 4; ++m)
#pragma unroll
      for (int n = 0; n < 4; ++n)
        acc[m][n] = __builtin_amdgcn_mfma_f32_16x16x32_bf16(af[m], bfv[n], acc[m][n], 0, 0, 0);
    __syncthreads();
  }

#pragma unroll
  for (int m = 0; m < 4; ++m) {
    const int srow_base = s0 + wr*64 + m*16 + fq*4;
#pragma unroll
    for (int n = 0; n < 4; ++n) {
      const int kk = col0 + wc*64 + n*16 + fr;
      const float bv = bg2[nz*KS + kk];
#pragma unroll
      for (int reg = 0; reg < 4; ++reg) {
        const int s = srow_base + reg;
        const float logit = acc[m][n][reg] + bv;
        const float g = 1.0f / (1.0f + expf(logit));   // 1 - sigmoid
        omg[(((size_t)(bb*NS + nz))*S_ + s)*KS + kk] = f2b(g);
      }
    }
  }
}

// ---------- Scan phase 1: per-chunk affine aggregates (A, B) ----------
__global__ __launch_bounds__(256) void scan_phase1(
    const unsigned short* __restrict__ omg,
    const unsigned short* __restrict__ dre,
    const unsigned short* __restrict__ dimv,
    float4* __restrict__ carry)
{
  const int c = blockIdx.x, n = blockIdx.y, bb = blockIdx.z;
  const int k = threadIdx.x;
  float ar, ai; a_base_of(n, ar, ai);
  size_t base = (((size_t)(bb*NS + n))*S_ + (size_t)c*CHUNK)*KS + k;
  float Are = 1.f, Aim = 0.f, Bre = 0.f, Bim = 0.f;
#pragma unroll 4
  for (int s = 0; s < CHUNK; ++s) {
    const size_t p = base + (size_t)s*KS;
    const float g  = b2f(omg[p]);
    const float are = g*ar, aie = g*ai;
    const float br = g * b2f(dre[p])  * INV16;
    const float bi = g * b2f(dimv[p]) * INV16;
    const float nAre = Are*are - Aim*aie;
    const float nAim = Are*aie + Aim*are;
    const float nBre = fmaf(are, Bre, fmaf(-aie, Bim, br));
    const float nBim = fmaf(are, Bim, fmaf( aie, Bre, bi));
    Are = nAre; Aim = nAim; Bre = nBre; Bim = nBim;
  }
  carry[(((size_t)(bb*NS + n))*NCHUNK + c)*KS + k] = make_float4(Are, Aim, Bre, Bim);
}

// ---------- Scan phase 2: sequential carry over chunks per chain ----------
__global__ __launch_bounds__(256) void scan_carry(
    const float4* __restrict__ carry, float2* __restrict__ Hst)
{
  const int idx = blockIdx.x*256 + threadIdx.x;   // 0..4095
  const int k  = idx & 255;
  const int bn = idx >> 8;                        // b*4+n
  float hre = 0.f, him = 0.f;
  const size_t base = ((size_t)bn)*NCHUNK*KS + k;
  for (int c = 0; c < NCHUNK; ++c) {
    Hst[base + (size_t)c*KS] = make_float2(hre, him);
    const float4 ab = carry[base + (size_t)c*KS];
    const float nre = fmaf(ab.x, hre, fmaf(-ab.y, him, ab.z));
    const float nim = fmaf(ab.x, him, fmaf( ab.y, hre, ab.w));
    hre = nre; him = nim;
  }
}

// ---------- Scan phase 3: replay with chunk-entry state, write output ----------
__global__ __launch_bounds__(256) void scan_phase3(
    const unsigned short* __restrict__ omg,
    const unsigned short* __restrict__ dre,
    const unsigned short* __restrict__ dimv,
    const float2* __restrict__ Hst,
    float* __restrict__ out)
{
  const int c = blockIdx.x, n = blockIdx.y, bb = blockIdx.z;
  const int k = threadIdx.x;
  float ar, ai; a_base_of(n, ar, ai);
  const float2 h0 = Hst[(((size_t)(bb*NS + n))*NCHUNK + c)*KS + k];
  float hre = h0.x, him = h0.y;
  size_t base = (((size_t)(bb*NS + n))*S_ + (size_t)c*CHUNK)*KS + k;
  size_t ob = (((size_t)bb)*S_ + (size_t)c*CHUNK)*2048 + (size_t)n*512 + k;
#pragma unroll 4
  for (int s = 0; s < CHUNK; ++s) {
    const size_t p = base + (size_t)s*KS;
    const float g  = b2f(omg[p]);
    const float are = g*ar, aie = g*ai;
    const float br = g * b2f(dre[p])  * INV16;
    const float bi = g * b2f(dimv[p]) * INV16;
    const float nre = fmaf(are, hre, fmaf(-aie, him, br));
    const float nim = fmaf(are, him, fmaf( aie, hre, bi));
    hre = nre; him = nim;
    out[ob + (size_t)s*2048      ] = hre;
    out[ob + (size_t)s*2048 + 256] = him;
  }
}

extern "C" void kernel_launch(void* const* d_in, const int* in_sizes, int n_in,
                              void* d_out, int out_size, void* d_ws, size_t ws_size,
                              hipStream_t stream) {
  const float* x   = (const float*)d_in[0];
  const float* Wg1 = (const float*)d_in[1];
  const float* bg1 = (const float*)d_in[2];
  const float* Wg2 = (const float*)d_in[3];
  const float* bg2 = (const float*)d_in[4];
  const float* Wre = (const float*)d_in[5];
  const float* bre = (const float*)d_in[6];
  const float* Wim = (const float*)d_in[7];
  const float* bim = (const float*)d_in[8];
  float* out = (float*)d_out;

  char* ws = (char*)d_ws;
  const size_t BUF = (size_t)B_*NS*S_*KS*sizeof(unsigned short);  // 32 MiB
  unsigned short* g1   = (unsigned short*)(ws);
  unsigned short* dre  = (unsigned short*)(ws + BUF);
  unsigned short* dimv = (unsigned short*)(ws + 2*BUF);
  unsigned short* omg  = (unsigned short*)(ws + 3*BUF);
  unsigned short* xb   = (unsigned short*)(ws + 4*BUF);           // 32 MiB (gemm1 only)
  unsigned short* Wb   = (unsigned short*)(ws + 5*BUF);           // 6 MiB
  unsigned short* Wg2t = (unsigned short*)(ws + 5*BUF + (size_t)3072*1024*2);
  // carry/Hst alias xb's region (xb is dead after gemm1)
  float4* carry = (float4*)(ws + 4*BUF);                          // 2 MiB
  float2* Hst   = (float2*)(ws + 4*BUF + (size_t)4*1024*1024);    // 1 MiB

  cvt_x<<<16384, 256, 0, stream>>>(x, xb);
  cvt_w1<<<dim3(8, 32, 12), 256, 0, stream>>>(Wg1, Wre, Wim, Wb);
  cvt_wg2<<<dim3(8, 8, 4), 256, 0, stream>>>(Wg2, Wg2t);

  gemm1_mfma<<<dim3(24, 128), 256, 0, stream>>>(xb, Wb, bg1, bre, bim, g1, dre, dimv);
  gemm2_mfma<<<dim3(2, 128, 4), 256, 0, stream>>>(g1, Wg2t, bg2, omg);

  scan_phase1<<<dim3(NCHUNK, NS, B_), 256, 0, stream>>>(omg, dre, dimv, carry);
  scan_carry<<<16, 256, 0, stream>>>(carry, Hst);
  scan_phase3<<<dim3(NCHUNK, NS, B_), 256, 0, stream>>>(omg, dre, dimv, Hst, out);
}

// Round 3
// 233.700 us; speedup vs baseline: 6.5055x; 1.0576x over previous
//
#include <hip/hip_runtime.h>
#include <hip/hip_bf16.h>

#define B_ 4
#define S_ 4096
#define DIN 1024
#define NS 4
#define KS 256
#define CHUNK 128
#define NCHUNK (S_/CHUNK)   // 32
#define INV16 0.0625f

typedef __bf16 bf16x8 __attribute__((ext_vector_type(8)));
typedef float f32x4 __attribute__((ext_vector_type(4)));

#define FENCE() asm volatile("" ::: "memory")
__device__ __forceinline__ void wait_vm4() { asm volatile("s_waitcnt vmcnt(4)" ::: "memory"); }
__device__ __forceinline__ void wait_vm0() { asm volatile("s_waitcnt vmcnt(0)" ::: "memory"); }

// ---------- bf16 helpers (raw ushort storage) ----------
__device__ __forceinline__ float b2f(unsigned short u) {
  union { unsigned int u; float f; } cv;
  cv.u = ((unsigned int)u) << 16;
  return cv.f;
}
__device__ __forceinline__ unsigned short f2b(float f) {
  union { float f; unsigned int u; } cv; cv.f = f;
  unsigned int u = cv.u;
  u += 0x7fffu + ((u >> 16) & 1u);   // round-to-nearest-even
  return (unsigned short)(u >> 16);
}

__device__ __forceinline__ void a_base_of(int n, float& ar, float& ai) {
  const float r[4]  = {1.0f, 0.999f, 0.9495f, 0.9f};
  const float th[4] = {0.0f, 0.01f, 0.505f, 1.0f};
  ar = r[n] * cosf(th[n]);
  ai = r[n] * sinf(th[n]);
}

__device__ __forceinline__ void glds16(const unsigned short* g, unsigned short* l) {
  __builtin_amdgcn_global_load_lds(
      (const __attribute__((address_space(1))) unsigned int*)g,
      (__attribute__((address_space(3))) unsigned int*)l, 16, 0, 0);
}

// ---------- conversion kernels ----------
__global__ __launch_bounds__(256) void cvt_x(const float* __restrict__ x,
                                             unsigned short* __restrict__ xb) {
  const size_t i = ((size_t)blockIdx.x*256 + threadIdx.x)*4;
  const float4 v = *reinterpret_cast<const float4*>(x + i);
  ushort4 o; o.x=f2b(v.x); o.y=f2b(v.y); o.z=f2b(v.z); o.w=f2b(v.w);
  *reinterpret_cast<ushort4*>(xb + i) = o;
}

// W[mat][n][1024 d][256 k] fp32  ->  Wb[mat*1024+n*256+k][1024 d] bf16
__global__ __launch_bounds__(256) void cvt_w1(const float* __restrict__ Wg1,
                                              const float* __restrict__ Wre,
                                              const float* __restrict__ Wim,
                                              unsigned short* __restrict__ Wb) {
  const int mn = blockIdx.z, mat = mn >> 2, n = mn & 3;
  const float* W = (mat==0) ? Wg1 : (mat==1 ? Wre : Wim);
  const float* src = W + (size_t)n*(DIN*KS);
  unsigned short* dst = Wb + (size_t)(mat*1024 + n*KS)*DIN;
  __shared__ float t[32][33];
  const int tx = threadIdx.x & 31, ty = threadIdx.x >> 5;
  const int d0 = blockIdx.y*32, k0 = blockIdx.x*32;
#pragma unroll
  for (int p = 0; p < 4; ++p)
    t[ty + p*8][tx] = src[(size_t)(d0 + ty + p*8)*KS + k0 + tx];
  __syncthreads();
#pragma unroll
  for (int p = 0; p < 4; ++p)
    dst[(size_t)(k0 + ty + p*8)*DIN + d0 + tx] = f2b(t[tx][ty + p*8]);
}

// Wg2[n][256 kin][256 kout] fp32 -> Wg2t[n][256 kout][256 kin] bf16
__global__ __launch_bounds__(256) void cvt_wg2(const float* __restrict__ Wg2,
                                               unsigned short* __restrict__ Wg2t) {
  const int n = blockIdx.z;
  const float* src = Wg2 + (size_t)n*(KS*KS);
  unsigned short* dst = Wg2t + (size_t)n*(KS*KS);
  __shared__ float t[32][33];
  const int tx = threadIdx.x & 31, ty = threadIdx.x >> 5;
  const int ki0 = blockIdx.y*32, ko0 = blockIdx.x*32;
#pragma unroll
  for (int p = 0; p < 4; ++p)
    t[ty + p*8][tx] = src[(size_t)(ki0 + ty + p*8)*KS + ko0 + tx];
  __syncthreads();
#pragma unroll
  for (int p = 0; p < 4; ++p)
    dst[(size_t)(ko0 + ty + p*8)*KS + ki0 + tx] = f2b(t[tx][ty + p*8]);
}

// ================= 256x256 8-phase GEMM core =================
// LDS: [dbuf][0=A,1=B][ks-half][256 rows][32 k] bf16, halves are contiguous 16 KiB.
typedef unsigned short LdsT[2][2][2][256][32];

template<int LDK>
__device__ __forceinline__ void stage_half(const unsigned short* __restrict__ gsrc,
                                           unsigned short* ldst, int tid, int kbase) {
#pragma unroll
  for (int i = 0; i < 2; ++i) {
    const int idx = i*512 + tid;           // 0..1023
    const int r  = idx >> 2;               // 0..255
    const int c8 = (idx & 3) << 3;         // 0,8,16,24
    glds16(gsrc + (size_t)r*LDK + kbase + c8, ldst + idx*8);
  }
}

#define LOAD_A(ks, mg) do { _Pragma("unroll") \
  for (int m = 0; m < 4; ++m) \
    af[m] = *(const bf16x8*)&lds[p][0][ks][wr*128 + (mg)*64 + m*16 + fr][fq*8]; } while(0)
#define LOAD_B(ks) do { _Pragma("unroll") \
  for (int n = 0; n < 4; ++n) \
    bf[n] = *(const bf16x8*)&lds[p][1][ks][wc*64 + n*16 + fr][fq*8]; } while(0)
#define DO_MFMA(mg) do { __builtin_amdgcn_s_setprio(1); _Pragma("unroll") \
  for (int m = 0; m < 4; ++m) { _Pragma("unroll") \
    for (int n = 0; n < 4; ++n) \
      acc[(mg)*4+m][n] = __builtin_amdgcn_mfma_f32_16x16x32_bf16(af[m], bf[n], acc[(mg)*4+m][n], 0, 0, 0); } \
  __builtin_amdgcn_s_setprio(0); } while(0)
#define BAR() do { FENCE(); __builtin_amdgcn_s_barrier(); FENCE(); } while(0)

template<int LDK, int NT>
__device__ __forceinline__ void kloop256(const unsigned short* __restrict__ gA,
                                         const unsigned short* __restrict__ gB,
                                         LdsT& lds, int tid, int wr, int wc, int fr, int fq,
                                         f32x4 (&acc)[8][4]) {
  // prologue: stage tile 0 fully into buf 0 (order: A.k0, B.k0, A.k1, B.k1)
  stage_half<LDK>(gA, &lds[0][0][0][0][0], tid, 0);
  stage_half<LDK>(gB, &lds[0][1][0][0][0], tid, 0);
  stage_half<LDK>(gA, &lds[0][0][1][0][0], tid, 32);
  stage_half<LDK>(gB, &lds[0][1][1][0][0], tid, 32);
  FENCE(); wait_vm4();           // k0 halves landed; k1 still in flight
  __builtin_amdgcn_s_barrier(); FENCE();

#pragma unroll 1
  for (int t = 0; t < NT; ++t) {
    const int p = t & 1, q = p ^ 1;
    const int kn = (t+1)*64;
    const bool more = (t+1 < NT);
    bf16x8 af[4], bf[4];
    // ---- phase 1: ks=0, m-group 0 ----
    LOAD_A(0, 0); LOAD_B(0);
    if (more) stage_half<LDK>(gA, &lds[q][0][0][0][0], tid, kn);
    BAR();
    DO_MFMA(0);
    BAR();
    // ---- phase 2: ks=0, m-group 1 ----
    LOAD_A(0, 1);
    if (more) stage_half<LDK>(gB, &lds[q][1][0][0][0], tid, kn);
    FENCE(); if (more) wait_vm4(); else wait_vm0();   // guarantees this tile's k1 halves
    __builtin_amdgcn_s_barrier(); FENCE();
    DO_MFMA(1);
    BAR();
    // ---- phase 3: ks=1, m-group 0 ----
    LOAD_A(1, 0); LOAD_B(1);
    if (more) stage_half<LDK>(gA, &lds[q][0][1][0][0], tid, kn + 32);
    BAR();
    DO_MFMA(0);
    BAR();
    // ---- phase 4: ks=1, m-group 1 ----
    LOAD_A(1, 1);
    if (more) stage_half<LDK>(gB, &lds[q][1][1][0][0], tid, kn + 32);
    FENCE(); if (more) wait_vm4(); else wait_vm0();   // guarantees next tile's k0 halves
    __builtin_amdgcn_s_barrier(); FENCE();
    DO_MFMA(1);
    BAR();
  }
}

// ---------- GEMM1: C[16384][3072] = xb @ Wb^T, scatter to g1/dre/dim ----------
__global__ __launch_bounds__(512, 2) void gemm1_8ph(
    const unsigned short* __restrict__ xb,   // [16384][1024]
    const unsigned short* __restrict__ Wb,   // [3072][1024]
    const float* __restrict__ bg1, const float* __restrict__ bre,
    const float* __restrict__ bim,
    unsigned short* __restrict__ g1, unsigned short* __restrict__ dre,
    unsigned short* __restrict__ dimv)
{
  __shared__ unsigned short lds[2][2][2][256][32];
  const int wg = blockIdx.x;                 // 768 = 8*96
  const int swz = (wg & 7)*96 + (wg >> 3);   // XCD-contiguous chunks
  const int ct = swz % 12, rt = swz / 12;
  const int row0 = rt*256, col0 = ct*256;
  const int tid = threadIdx.x, lane = tid & 63, wid = tid >> 6;
  const int wr = wid >> 2, wc = wid & 3, fr = lane & 15, fq = lane >> 4;

  const unsigned short* gA = xb + (size_t)row0*DIN;
  const unsigned short* gB = Wb + (size_t)col0*DIN;

  f32x4 acc[8][4];
#pragma unroll
  for (int m = 0; m < 8; ++m)
#pragma unroll
    for (int n = 0; n < 4; ++n) acc[m][n] = (f32x4){0.f,0.f,0.f,0.f};

  kloop256<DIN, DIN/64>(gA, gB, (LdsT&)lds, tid, wr, wc, fr, fq, acc);

  const int mat = ct >> 2, nsc = ct & 3;     // col0 = (mat*4+nsc)*256
  const float* bias = (mat==0) ? bg1 : (mat==1 ? bre : bim);
  unsigned short* dst = (mat==0) ? g1 : (mat==1 ? dre : dimv);

#pragma unroll
  for (int mm = 0; mm < 8; ++mm) {
    const int grow_base = row0 + wr*128 + mm*16 + fq*4;
#pragma unroll
    for (int n = 0; n < 4; ++n) {
      const int kk = wc*64 + n*16 + fr;
      const float bv = bias[nsc*KS + kk];
#pragma unroll
      for (int reg = 0; reg < 4; ++reg) {
        const int grow = grow_base + reg;
        const int bb = grow >> 12, s = grow & 4095;
        float v = acc[mm][n][reg] + bv;
        if (mat == 0) v = fmaxf(v, 0.f);
        dst[(((size_t)(bb*NS + nsc))*S_ + s)*KS + kk] = f2b(v);
      }
    }
  }
}

// ---------- GEMM2: omg = 1 - sigmoid(g1 @ Wg2 + bg2) ----------
__global__ __launch_bounds__(512, 2) void gemm2_8ph(
    const unsigned short* __restrict__ g1,     // ((bb*NS+n)*S+s)*256 + k
    const unsigned short* __restrict__ Wg2t,   // [n][256 kout][256 kin]
    const float* __restrict__ bg2,
    unsigned short* __restrict__ omg)
{
  __shared__ unsigned short lds[2][2][2][256][32];
  const int wg = blockIdx.x;                 // 256 = 8*32
  const int swz = (wg & 7)*32 + (wg >> 3);
  const int nz = swz >> 6, rowIdx = swz & 63;
  const int bb = rowIdx >> 4, st = rowIdx & 15;
  const int s0 = st*256;
  const int tid = threadIdx.x, lane = tid & 63, wid = tid >> 6;
  const int wr = wid >> 2, wc = wid & 3, fr = lane & 15, fq = lane >> 4;

  const unsigned short* gA = g1 + ((size_t)(bb*NS + nz)*S_ + s0)*KS;
  const unsigned short* gB = Wg2t + (size_t)nz*KS*KS;

  f32x4 acc[8][4];
#pragma unroll
  for (int m = 0; m < 8; ++m)
#pragma unroll
    for (int n = 0; n < 4; ++n) acc[m][n] = (f32x4){0.f,0.f,0.f,0.f};

  kloop256<KS, KS/64>(gA, gB, (LdsT&)lds, tid, wr, wc, fr, fq, acc);

#pragma unroll
  for (int mm = 0; mm < 8; ++mm) {
    const int srow_base = s0 + wr*128 + mm*16 + fq*4;
#pragma unroll
    for (int n = 0; n < 4; ++n) {
      const int kk = wc*64 + n*16 + fr;
      const float bv = bg2[nz*KS + kk];
#pragma unroll
      for (int reg = 0; reg < 4; ++reg) {
        const int s = srow_base + reg;
        const float logit = acc[mm][n][reg] + bv;
        const float g = 1.0f / (1.0f + expf(logit));   // 1 - sigmoid
        omg[(((size_t)(bb*NS + nz))*S_ + s)*KS + kk] = f2b(g);
      }
    }
  }
}

// ---------- Scan phase 1: per-chunk affine aggregates (A, B) ----------
__global__ __launch_bounds__(256) void scan_phase1(
    const unsigned short* __restrict__ omg,
    const unsigned short* __restrict__ dre,
    const unsigned short* __restrict__ dimv,
    float4* __restrict__ carry)
{
  const int c = blockIdx.x, n = blockIdx.y, bb = blockIdx.z;
  const int k = threadIdx.x;
  float ar, ai; a_base_of(n, ar, ai);
  size_t base = (((size_t)(bb*NS + n))*S_ + (size_t)c*CHUNK)*KS + k;
  float Are = 1.f, Aim = 0.f, Bre = 0.f, Bim = 0.f;
#pragma unroll 4
  for (int s = 0; s < CHUNK; ++s) {
    const size_t p = base + (size_t)s*KS;
    const float g  = b2f(omg[p]);
    const float are = g*ar, aie = g*ai;
    const float br = g * b2f(dre[p])  * INV16;
    const float bi = g * b2f(dimv[p]) * INV16;
    const float nAre = Are*are - Aim*aie;
    const float nAim = Are*aie + Aim*are;
    const float nBre = fmaf(are, Bre, fmaf(-aie, Bim, br));
    const float nBim = fmaf(are, Bim, fmaf( aie, Bre, bi));
    Are = nAre; Aim = nAim; Bre = nBre; Bim = nBim;
  }
  carry[(((size_t)(bb*NS + n))*NCHUNK + c)*KS + k] = make_float4(Are, Aim, Bre, Bim);
}

// ---------- Scan phase 2: sequential carry over chunks per chain ----------
__global__ __launch_bounds__(256) void scan_carry(
    const float4* __restrict__ carry, float2* __restrict__ Hst)
{
  const int idx = blockIdx.x*256 + threadIdx.x;   // 0..4095
  const int k  = idx & 255;
  const int bn = idx >> 8;
  float hre = 0.f, him = 0.f;
  const size_t base = ((size_t)bn)*NCHUNK*KS + k;
  for (int c = 0; c < NCHUNK; ++c) {
    Hst[base + (size_t)c*KS] = make_float2(hre, him);
    const float4 ab = carry[base + (size_t)c*KS];
    const float nre = fmaf(ab.x, hre, fmaf(-ab.y, him, ab.z));
    const float nim = fmaf(ab.x, him, fmaf( ab.y, hre, ab.w));
    hre = nre; him = nim;
  }
}

// ---------- Scan phase 3: replay with chunk-entry state, write output ----------
__global__ __launch_bounds__(256) void scan_phase3(
    const unsigned short* __restrict__ omg,
    const unsigned short* __restrict__ dre,
    const unsigned short* __restrict__ dimv,
    const float2* __restrict__ Hst,
    float* __restrict__ out)
{
  const int c = blockIdx.x, n = blockIdx.y, bb = blockIdx.z;
  const int k = threadIdx.x;
  float ar, ai; a_base_of(n, ar, ai);
  const float2 h0 = Hst[(((size_t)(bb*NS + n))*NCHUNK + c)*KS + k];
  float hre = h0.x, him = h0.y;
  size_t base = (((size_t)(bb*NS + n))*S_ + (size_t)c*CHUNK)*KS + k;
  size_t ob = (((size_t)bb)*S_ + (size_t)c*CHUNK)*2048 + (size_t)n*512 + k;
#pragma unroll 4
  for (int s = 0; s < CHUNK; ++s) {
    const size_t p = base + (size_t)s*KS;
    const float g  = b2f(omg[p]);
    const float are = g*ar, aie = g*ai;
    const float br = g * b2f(dre[p])  * INV16;
    const float bi = g * b2f(dimv[p]) * INV16;
    const float nre = fmaf(are, hre, fmaf(-aie, him, br));
    const float nim = fmaf(are, him, fmaf( aie, hre, bi));
    hre = nre; him = nim;
    out[ob + (size_t)s*2048      ] = hre;
    out[ob + (size_t)s*2048 + 256] = him;
  }
}

extern "C" void kernel_launch(void* const* d_in, const int* in_sizes, int n_in,
                              void* d_out, int out_size, void* d_ws, size_t ws_size,
                              hipStream_t stream) {
  const float* x   = (const float*)d_in[0];
  const float* Wg1 = (const float*)d_in[1];
  const float* bg1 = (const float*)d_in[2];
  const float* Wg2 = (const float*)d_in[3];
  const float* bg2 = (const float*)d_in[4];
  const float* Wre = (const float*)d_in[5];
  const float* bre = (const float*)d_in[6];
  const float* Wim = (const float*)d_in[7];
  const float* bim = (const float*)d_in[8];
  float* out = (float*)d_out;

  char* ws = (char*)d_ws;
  const size_t BUF = (size_t)B_*NS*S_*KS*sizeof(unsigned short);  // 32 MiB
  unsigned short* g1   = (unsigned short*)(ws);
  unsigned short* dre  = (unsigned short*)(ws + BUF);
  unsigned short* dimv = (unsigned short*)(ws + 2*BUF);
  unsigned short* omg  = (unsigned short*)(ws + 3*BUF);
  unsigned short* xb   = (unsigned short*)(ws + 4*BUF);           // 32 MiB (gemm1 only)
  unsigned short* Wb   = (unsigned short*)(ws + 5*BUF);           // 6 MiB
  unsigned short* Wg2t = (unsigned short*)(ws + 5*BUF + (size_t)3072*1024*2);
  // carry/Hst alias xb's region (xb is dead after gemm1)
  float4* carry = (float4*)(ws + 4*BUF);
  float2* Hst   = (float2*)(ws + 4*BUF + (size_t)4*1024*1024);

  cvt_x<<<16384, 256, 0, stream>>>(x, xb);
  cvt_w1<<<dim3(8, 32, 12), 256, 0, stream>>>(Wg1, Wre, Wim, Wb);
  cvt_wg2<<<dim3(8, 8, 4), 256, 0, stream>>>(Wg2, Wg2t);

  gemm1_8ph<<<768, 512, 0, stream>>>(xb, Wb, bg1, bre, bim, g1, dre, dimv);
  gemm2_8ph<<<256, 512, 0, stream>>>(g1, Wg2t, bg2, omg);

  scan_phase1<<<dim3(NCHUNK, NS, B_), 256, 0, stream>>>(omg, dre, dimv, carry);
  scan_carry<<<16, 256, 0, stream>>>(carry, Hst);
  scan_phase3<<<dim3(NCHUNK, NS, B_), 256, 0, stream>>>(omg, dre, dimv, Hst, out);
}

// Round 4
// 228.471 us; speedup vs baseline: 6.6544x; 1.0229x over previous
//
#include <hip/hip_runtime.h>
#include <hip/hip_bf16.h>

#define B_ 4
#define S_ 4096
#define DIN 1024
#define NS 4
#define KS 256
#define CHUNK 128
#define NCHUNK (S_/CHUNK)   // 32
#define INV16 0.0625f

typedef __bf16 bf16x8 __attribute__((ext_vector_type(8)));
typedef float f32x4 __attribute__((ext_vector_type(4)));

#define FENCE() asm volatile("" ::: "memory")
__device__ __forceinline__ void wait_vm4() { asm volatile("s_waitcnt vmcnt(4)" ::: "memory"); }
__device__ __forceinline__ void wait_vm0() { asm volatile("s_waitcnt vmcnt(0)" ::: "memory"); }

// ---------- bf16 helpers (raw ushort storage) ----------
__device__ __forceinline__ float b2f(unsigned short u) {
  union { unsigned int u; float f; } cv;
  cv.u = ((unsigned int)u) << 16;
  return cv.f;
}
__device__ __forceinline__ unsigned short f2b(float f) {
  union { float f; unsigned int u; } cv; cv.f = f;
  unsigned int u = cv.u;
  u += 0x7fffu + ((u >> 16) & 1u);   // round-to-nearest-even
  return (unsigned short)(u >> 16);
}

__device__ __forceinline__ void a_base_of(int n, float& ar, float& ai) {
  const float r[4]  = {1.0f, 0.999f, 0.9495f, 0.9f};
  const float th[4] = {0.0f, 0.01f, 0.505f, 1.0f};
  ar = r[n] * cosf(th[n]);
  ai = r[n] * sinf(th[n]);
}

__device__ __forceinline__ void glds16(const unsigned short* g, unsigned short* l) {
  __builtin_amdgcn_global_load_lds(
      (const __attribute__((address_space(1))) unsigned int*)g,
      (__attribute__((address_space(3))) unsigned int*)l, 16, 0, 0);
}

// ---------- conversion kernels ----------
__global__ __launch_bounds__(256) void cvt_x(const float* __restrict__ x,
                                             unsigned short* __restrict__ xb) {
  const size_t i = ((size_t)blockIdx.x*256 + threadIdx.x)*4;
  const float4 v = *reinterpret_cast<const float4*>(x + i);
  ushort4 o; o.x=f2b(v.x); o.y=f2b(v.y); o.z=f2b(v.z); o.w=f2b(v.w);
  *reinterpret_cast<ushort4*>(xb + i) = o;
}

// W[mat][n][1024 d][256 k] fp32  ->  Wb[mat*1024+n*256+k][1024 d] bf16
__global__ __launch_bounds__(256) void cvt_w1(const float* __restrict__ Wg1,
                                              const float* __restrict__ Wre,
                                              const float* __restrict__ Wim,
                                              unsigned short* __restrict__ Wb) {
  const int mn = blockIdx.z, mat = mn >> 2, n = mn & 3;
  const float* W = (mat==0) ? Wg1 : (mat==1 ? Wre : Wim);
  const float* src = W + (size_t)n*(DIN*KS);
  unsigned short* dst = Wb + (size_t)(mat*1024 + n*KS)*DIN;
  __shared__ float t[32][33];
  const int tx = threadIdx.x & 31, ty = threadIdx.x >> 5;
  const int d0 = blockIdx.y*32, k0 = blockIdx.x*32;
#pragma unroll
  for (int p = 0; p < 4; ++p)
    t[ty + p*8][tx] = src[(size_t)(d0 + ty + p*8)*KS + k0 + tx];
  __syncthreads();
#pragma unroll
  for (int p = 0; p < 4; ++p)
    dst[(size_t)(k0 + ty + p*8)*DIN + d0 + tx] = f2b(t[tx][ty + p*8]);
}

// Wg2[n][256 kin][256 kout] fp32 -> Wg2t[n][256 kout][256 kin] bf16
__global__ __launch_bounds__(256) void cvt_wg2(const float* __restrict__ Wg2,
                                               unsigned short* __restrict__ Wg2t) {
  const int n = blockIdx.z;
  const float* src = Wg2 + (size_t)n*(KS*KS);
  unsigned short* dst = Wg2t + (size_t)n*(KS*KS);
  __shared__ float t[32][33];
  const int tx = threadIdx.x & 31, ty = threadIdx.x >> 5;
  const int ki0 = blockIdx.y*32, ko0 = blockIdx.x*32;
#pragma unroll
  for (int p = 0; p < 4; ++p)
    t[ty + p*8][tx] = src[(size_t)(ki0 + ty + p*8)*KS + ko0 + tx];
  __syncthreads();
#pragma unroll
  for (int p = 0; p < 4; ++p)
    dst[(size_t)(ko0 + ty + p*8)*KS + ki0 + tx] = f2b(t[tx][ty + p*8]);
}

// ================= 256x256 8-phase GEMM core =================
// LDS: [dbuf][0=A,1=B][ks-half][256 rows][32 k] bf16, 64-B rows = 4 x 16B slots.
// Slot swizzle: physical slot = logical_slot ^ ((row>>1)&3)  (involution).
// global_load_lds dest stays LINEAR; the global SOURCE column is pre-swizzled,
// and fragment reads apply the same XOR (rule: both-sides-or-neither).
typedef unsigned short LdsT[2][2][2][256][32];

template<int LDK>
__device__ __forceinline__ void stage_half(const unsigned short* __restrict__ gsrc,
                                           unsigned short* ldst, int tid, int kbase) {
#pragma unroll
  for (int i = 0; i < 2; ++i) {
    const int idx = i*512 + tid;           // 0..1023
    const int r  = idx >> 2;               // 0..255
    const int s  = idx & 3;                // physical 16B slot
    const int c8 = (s ^ ((r >> 1) & 3)) << 3;   // swizzled global column group
    glds16(gsrc + (size_t)r*LDK + kbase + c8, ldst + idx*8);
  }
}

#define LOAD_A(ks, mg) do { _Pragma("unroll") \
  for (int m = 0; m < 4; ++m) \
    af[m] = *(const bf16x8*)&lds[p][0][ks][wr*128 + (mg)*64 + m*16 + fr][(fq ^ swl)*8]; } while(0)
#define LOAD_B(ks) do { _Pragma("unroll") \
  for (int n = 0; n < 4; ++n) \
    bf[n] = *(const bf16x8*)&lds[p][1][ks][wc*64 + n*16 + fr][(fq ^ swl)*8]; } while(0)
#define DO_MFMA(mg) do { __builtin_amdgcn_s_setprio(1); _Pragma("unroll") \
  for (int m = 0; m < 4; ++m) { _Pragma("unroll") \
    for (int n = 0; n < 4; ++n) \
      acc[(mg)*4+m][n] = __builtin_amdgcn_mfma_f32_16x16x32_bf16(af[m], bf[n], acc[(mg)*4+m][n], 0, 0, 0); } \
  __builtin_amdgcn_s_setprio(0); } while(0)
#define BAR() do { FENCE(); __builtin_amdgcn_s_barrier(); FENCE(); } while(0)

template<int LDK, int NT>
__device__ __forceinline__ void kloop256(const unsigned short* __restrict__ gA,
                                         const unsigned short* __restrict__ gB,
                                         LdsT& lds, int tid, int wr, int wc, int fr, int fq,
                                         f32x4 (&acc)[8][4]) {
  const int swl = (fr >> 1) & 3;   // row-derived slot XOR (row%16 == fr for all fragment rows)
  // prologue: stage tile 0 fully into buf 0 (order: A.k0, B.k0, A.k1, B.k1)
  stage_half<LDK>(gA, &lds[0][0][0][0][0], tid, 0);
  stage_half<LDK>(gB, &lds[0][1][0][0][0], tid, 0);
  stage_half<LDK>(gA, &lds[0][0][1][0][0], tid, 32);
  stage_half<LDK>(gB, &lds[0][1][1][0][0], tid, 32);
  FENCE(); wait_vm4();           // k0 halves landed; k1 still in flight
  __builtin_amdgcn_s_barrier(); FENCE();

#pragma unroll 1
  for (int t = 0; t < NT; ++t) {
    const int p = t & 1, q = p ^ 1;
    const int kn = (t+1)*64;
    const bool more = (t+1 < NT);
    bf16x8 af[4], bf[4];
    // ---- phase 1: ks=0, m-group 0 ----
    LOAD_A(0, 0); LOAD_B(0);
    if (more) stage_half<LDK>(gA, &lds[q][0][0][0][0], tid, kn);
    BAR();
    DO_MFMA(0);
    BAR();
    // ---- phase 2: ks=0, m-group 1 ----
    LOAD_A(0, 1);
    if (more) stage_half<LDK>(gB, &lds[q][1][0][0][0], tid, kn);
    FENCE(); if (more) wait_vm4(); else wait_vm0();   // guarantees this tile's k1 halves
    __builtin_amdgcn_s_barrier(); FENCE();
    DO_MFMA(1);
    BAR();
    // ---- phase 3: ks=1, m-group 0 ----
    LOAD_A(1, 0); LOAD_B(1);
    if (more) stage_half<LDK>(gA, &lds[q][0][1][0][0], tid, kn + 32);
    BAR();
    DO_MFMA(0);
    BAR();
    // ---- phase 4: ks=1, m-group 1 ----
    LOAD_A(1, 1);
    if (more) stage_half<LDK>(gB, &lds[q][1][1][0][0], tid, kn + 32);
    FENCE(); if (more) wait_vm4(); else wait_vm0();   // guarantees next tile's k0 halves
    __builtin_amdgcn_s_barrier(); FENCE();
    DO_MFMA(1);
    BAR();
  }
}

// ---------- GEMM1: C[16384][3072] = xb @ Wb^T, scatter to g1/dre/dim ----------
__global__ __launch_bounds__(512, 2) void gemm1_8ph(
    const unsigned short* __restrict__ xb,   // [16384][1024]
    const unsigned short* __restrict__ Wb,   // [3072][1024]
    const float* __restrict__ bg1, const float* __restrict__ bre,
    const float* __restrict__ bim,
    unsigned short* __restrict__ g1, unsigned short* __restrict__ dre,
    unsigned short* __restrict__ dimv)
{
  __shared__ unsigned short lds[2][2][2][256][32];
  const int wg = blockIdx.x;                 // 768 = 8*96
  const int swz = (wg & 7)*96 + (wg >> 3);   // XCD-contiguous chunks
  const int ct = swz % 12, rt = swz / 12;
  const int row0 = rt*256, col0 = ct*256;
  const int tid = threadIdx.x, lane = tid & 63, wid = tid >> 6;
  const int wr = wid >> 2, wc = wid & 3, fr = lane & 15, fq = lane >> 4;

  const unsigned short* gA = xb + (size_t)row0*DIN;
  const unsigned short* gB = Wb + (size_t)col0*DIN;

  f32x4 acc[8][4];
#pragma unroll
  for (int m = 0; m < 8; ++m)
#pragma unroll
    for (int n = 0; n < 4; ++n) acc[m][n] = (f32x4){0.f,0.f,0.f,0.f};

  kloop256<DIN, DIN/64>(gA, gB, (LdsT&)lds, tid, wr, wc, fr, fq, acc);

  const int mat = ct >> 2, nsc = ct & 3;     // col0 = (mat*4+nsc)*256
  const float* bias = (mat==0) ? bg1 : (mat==1 ? bre : bim);
  unsigned short* dst = (mat==0) ? g1 : (mat==1 ? dre : dimv);

#pragma unroll
  for (int mm = 0; mm < 8; ++mm) {
    const int grow_base = row0 + wr*128 + mm*16 + fq*4;
#pragma unroll
    for (int n = 0; n < 4; ++n) {
      const int kk = wc*64 + n*16 + fr;
      const float bv = bias[nsc*KS + kk];
#pragma unroll
      for (int reg = 0; reg < 4; ++reg) {
        const int grow = grow_base + reg;
        const int bb = grow >> 12, s = grow & 4095;
        float v = acc[mm][n][reg] + bv;
        if (mat == 0) v = fmaxf(v, 0.f);
        dst[(((size_t)(bb*NS + nsc))*S_ + s)*KS + kk] = f2b(v);
      }
    }
  }
}

// ---------- GEMM2: omg = 1 - sigmoid(g1 @ Wg2 + bg2) ----------
__global__ __launch_bounds__(512, 2) void gemm2_8ph(
    const unsigned short* __restrict__ g1,     // ((bb*NS+n)*S+s)*256 + k
    const unsigned short* __restrict__ Wg2t,   // [n][256 kout][256 kin]
    const float* __restrict__ bg2,
    unsigned short* __restrict__ omg)
{
  __shared__ unsigned short lds[2][2][2][256][32];
  const int wg = blockIdx.x;                 // 256 = 8*32
  const int swz = (wg & 7)*32 + (wg >> 3);
  const int nz = swz >> 6, rowIdx = swz & 63;
  const int bb = rowIdx >> 4, st = rowIdx & 15;
  const int s0 = st*256;
  const int tid = threadIdx.x, lane = tid & 63, wid = tid >> 6;
  const int wr = wid >> 2, wc = wid & 3, fr = lane & 15, fq = lane >> 4;

  const unsigned short* gA = g1 + ((size_t)(bb*NS + nz)*S_ + s0)*KS;
  const unsigned short* gB = Wg2t + (size_t)nz*KS*KS;

  f32x4 acc[8][4];
#pragma unroll
  for (int m = 0; m < 8; ++m)
#pragma unroll
    for (int n = 0; n < 4; ++n) acc[m][n] = (f32x4){0.f,0.f,0.f,0.f};

  kloop256<KS, KS/64>(gA, gB, (LdsT&)lds, tid, wr, wc, fr, fq, acc);

#pragma unroll
  for (int mm = 0; mm < 8; ++mm) {
    const int srow_base = s0 + wr*128 + mm*16 + fq*4;
#pragma unroll
    for (int n = 0; n < 4; ++n) {
      const int kk = wc*64 + n*16 + fr;
      const float bv = bg2[nz*KS + kk];
#pragma unroll
      for (int reg = 0; reg < 4; ++reg) {
        const int s = srow_base + reg;
        const float logit = acc[mm][n][reg] + bv;
        const float g = 1.0f / (1.0f + expf(logit));   // 1 - sigmoid
        omg[(((size_t)(bb*NS + nz))*S_ + s)*KS + kk] = f2b(g);
      }
    }
  }
}

// ---------- Scan phase 1: per-chunk affine aggregates (A, B) ----------
__global__ __launch_bounds__(256) void scan_phase1(
    const unsigned short* __restrict__ omg,
    const unsigned short* __restrict__ dre,
    const unsigned short* __restrict__ dimv,
    float4* __restrict__ carry)
{
  const int c = blockIdx.x, n = blockIdx.y, bb = blockIdx.z;
  const int k = threadIdx.x;
  float ar, ai; a_base_of(n, ar, ai);
  size_t base = (((size_t)(bb*NS + n))*S_ + (size_t)c*CHUNK)*KS + k;
  float Are = 1.f, Aim = 0.f, Bre = 0.f, Bim = 0.f;
#pragma unroll 4
  for (int s = 0; s < CHUNK; ++s) {
    const size_t p = base + (size_t)s*KS;
    const float g  = b2f(omg[p]);
    const float are = g*ar, aie = g*ai;
    const float br = g * b2f(dre[p])  * INV16;
    const float bi = g * b2f(dimv[p]) * INV16;
    const float nAre = Are*are - Aim*aie;
    const float nAim = Are*aie + Aim*are;
    const float nBre = fmaf(are, Bre, fmaf(-aie, Bim, br));
    const float nBim = fmaf(are, Bim, fmaf( aie, Bre, bi));
    Are = nAre; Aim = nAim; Bre = nBre; Bim = nBim;
  }
  carry[(((size_t)(bb*NS + n))*NCHUNK + c)*KS + k] = make_float4(Are, Aim, Bre, Bim);
}

// ---------- Scan phase 2: sequential carry over chunks per chain ----------
__global__ __launch_bounds__(256) void scan_carry(
    const float4* __restrict__ carry, float2* __restrict__ Hst)
{
  const int idx = blockIdx.x*256 + threadIdx.x;   // 0..4095
  const int k  = idx & 255;
  const int bn = idx >> 8;
  float hre = 0.f, him = 0.f;
  const size_t base = ((size_t)bn)*NCHUNK*KS + k;
  for (int c = 0; c < NCHUNK; ++c) {
    Hst[base + (size_t)c*KS] = make_float2(hre, him);
    const float4 ab = carry[base + (size_t)c*KS];
    const float nre = fmaf(ab.x, hre, fmaf(-ab.y, him, ab.z));
    const float nim = fmaf(ab.x, him, fmaf( ab.y, hre, ab.w));
    hre = nre; him = nim;
  }
}

// ---------- Scan phase 3: replay with chunk-entry state, write output ----------
__global__ __launch_bounds__(256) void scan_phase3(
    const unsigned short* __restrict__ omg,
    const unsigned short* __restrict__ dre,
    const unsigned short* __restrict__ dimv,
    const float2* __restrict__ Hst,
    float* __restrict__ out)
{
  const int c = blockIdx.x, n = blockIdx.y, bb = blockIdx.z;
  const int k = threadIdx.x;
  float ar, ai; a_base_of(n, ar, ai);
  const float2 h0 = Hst[(((size_t)(bb*NS + n))*NCHUNK + c)*KS + k];
  float hre = h0.x, him = h0.y;
  size_t base = (((size_t)(bb*NS + n))*S_ + (size_t)c*CHUNK)*KS + k;
  size_t ob = (((size_t)bb)*S_ + (size_t)c*CHUNK)*2048 + (size_t)n*512 + k;
#pragma unroll 4
  for (int s = 0; s < CHUNK; ++s) {
    const size_t p = base + (size_t)s*KS;
    const float g  = b2f(omg[p]);
    const float are = g*ar, aie = g*ai;
    const float br = g * b2f(dre[p])  * INV16;
    const float bi = g * b2f(dimv[p]) * INV16;
    const float nre = fmaf(are, hre, fmaf(-aie, him, br));
    const float nim = fmaf(are, him, fmaf( aie, hre, bi));
    hre = nre; him = nim;
    out[ob + (size_t)s*2048      ] = hre;
    out[ob + (size_t)s*2048 + 256] = him;
  }
}

extern "C" void kernel_launch(void* const* d_in, const int* in_sizes, int n_in,
                              void* d_out, int out_size, void* d_ws, size_t ws_size,
                              hipStream_t stream) {
  const float* x   = (const float*)d_in[0];
  const float* Wg1 = (const float*)d_in[1];
  const float* bg1 = (const float*)d_in[2];
  const float* Wg2 = (const float*)d_in[3];
  const float* bg2 = (const float*)d_in[4];
  const float* Wre = (const float*)d_in[5];
  const float* bre = (const float*)d_in[6];
  const float* Wim = (const float*)d_in[7];
  const float* bim = (const float*)d_in[8];
  float* out = (float*)d_out;

  char* ws = (char*)d_ws;
  const size_t BUF = (size_t)B_*NS*S_*KS*sizeof(unsigned short);  // 32 MiB
  unsigned short* g1   = (unsigned short*)(ws);
  unsigned short* dre  = (unsigned short*)(ws + BUF);
  unsigned short* dimv = (unsigned short*)(ws + 2*BUF);
  unsigned short* omg  = (unsigned short*)(ws + 3*BUF);
  unsigned short* xb   = (unsigned short*)(ws + 4*BUF);           // 32 MiB (gemm1 only)
  unsigned short* Wb   = (unsigned short*)(ws + 5*BUF);           // 6 MiB
  unsigned short* Wg2t = (unsigned short*)(ws + 5*BUF + (size_t)3072*1024*2);
  // carry/Hst alias xb's region (xb is dead after gemm1)
  float4* carry = (float4*)(ws + 4*BUF);
  float2* Hst   = (float2*)(ws + 4*BUF + (size_t)4*1024*1024);

  cvt_x<<<16384, 256, 0, stream>>>(x, xb);
  cvt_w1<<<dim3(8, 32, 12), 256, 0, stream>>>(Wg1, Wre, Wim, Wb);
  cvt_wg2<<<dim3(8, 8, 4), 256, 0, stream>>>(Wg2, Wg2t);

  gemm1_8ph<<<768, 512, 0, stream>>>(xb, Wb, bg1, bre, bim, g1, dre, dimv);
  gemm2_8ph<<<256, 512, 0, stream>>>(g1, Wg2t, bg2, omg);

  scan_phase1<<<dim3(NCHUNK, NS, B_), 256, 0, stream>>>(omg, dre, dimv, carry);
  scan_carry<<<16, 256, 0, stream>>>(carry, Hst);
  scan_phase3<<<dim3(NCHUNK, NS, B_), 256, 0, stream>>>(omg, dre, dimv, Hst, out);
}